// Round 8
// baseline (235.633 us; speedup 1.0000x reference)
//
#include <hip/hip_runtime.h>

#define DIM 640
#define NHEADS 10
#define HDIM 64
#define SEQ 1024
#define BATCH 16
#define MROWS (BATCH * SEQ)   // 16384
#define QKVN (3 * DIM)        // 1920
#define NBH (BATCH * NHEADS)  // 160

typedef float f32x4 __attribute__((ext_vector_type(4)));
typedef __bf16 bf16x8 __attribute__((ext_vector_type(8)));

// 640^-0.5 * log2(e) — folded into Q at K1 epilogue
#define SM_C 0.057027536f

// hardware bf16 convert (v_cvt_pk_bf16_f32 on gfx950), RNE
__device__ __forceinline__ unsigned short f2b(float f) {
  union { __bf16 h; unsigned short u; } v;
  v.h = (__bf16)f;
  return v.u;
}

__device__ __forceinline__ f32x4 mfma16(bf16x8 a, bf16x8 b, f32x4 c) {
  return __builtin_amdgcn_mfma_f32_16x16x32_bf16(a, b, c, 0, 0, 0);
}

// async global->LDS, 16B per lane. dest base wave-uniform; lane i lands at
// dest + i*16B. XOR swizzle is encoded in the per-lane SOURCE address.
typedef __attribute__((address_space(3))) unsigned int as3_u32;
typedef const __attribute__((address_space(1))) unsigned int as1_u32;
__device__ __forceinline__ void glds16(const unsigned short* g, unsigned short* l) {
  __builtin_amdgcn_global_load_lds((as1_u32*)g, (as3_u32*)l, 16, 0, 0);
}

// kv row remap for K staging: LDS row y holds source kv row kv_remap(y).
// Within each 32-kv chunk: tile-A rows (y&31 < 16) hold kv 8Q+r (r<4),
// tile-B rows hold kv 8Q+r+4. After S^T = mfma(K,Q), lane 'quad' then holds
// kv = 8*quad + 0..7 for its q-row across the (A,B) tile pair — exactly the
// A-operand layout of the K=32 MFMA. PV runs at full rate, no cross-lane ops.
__device__ __forceinline__ int kv_remap(int y) {
  return 32 * (y >> 5) + 8 * ((y & 15) >> 2) + (y & 3) + 4 * ((y >> 4) & 1);
}

// ---------------------------------------------------------------------------
// K0a: x fp32 -> bf16, same layout.
// ---------------------------------------------------------------------------
__global__ __launch_bounds__(256) void convert_x(
    const float* __restrict__ X, unsigned short* __restrict__ xb) {
  int i = (blockIdx.x * 256 + threadIdx.x) * 4;
  float4 v = *(const float4*)(X + i);
  ushort4 s;
  s.x = f2b(v.x); s.y = f2b(v.y); s.z = f2b(v.z); s.w = f2b(v.w);
  *(ushort4*)(xb + i) = s;
}

// ---------------------------------------------------------------------------
// K0b: W fp32 [R][C] -> Wt bf16 [C][R] (transpose+convert).
// ---------------------------------------------------------------------------
__global__ __launch_bounds__(256) void transpose_w(
    const float* __restrict__ W, unsigned short* __restrict__ Wt, int R, int C) {
  __shared__ int tile[32][33];
  const int tx = threadIdx.x & 31, ty = threadIdx.x >> 5;   // ty 0..7
  const int c0 = blockIdx.x * 32, r0 = blockIdx.y * 32;
#pragma unroll
  for (int i = 0; i < 4; ++i)
    tile[ty + 8 * i][tx] = f2b(W[(r0 + ty + 8 * i) * C + c0 + tx]);
  __syncthreads();
#pragma unroll
  for (int i = 0; i < 4; ++i)
    Wt[(c0 + ty + 8 * i) * R + r0 + tx] = (unsigned short)tile[tx][ty + 8 * i];
}

// ---------------------------------------------------------------------------
// K1: qkv = xb @ w_qkv^T-staged + b. Scatters Q (pre-scaled by SM_C), K into
// [bh][n][64]; V into [bh][64][n] (pre-transposed).
// 256x128 tile, 8 waves (512 thr), BK=64, single-buffer 2-barrier K-loop.
// LDS 48KB: As 256x64 (32K) + Bs 128x64 (16K). Conflict-free 128B-row
// swizzle. Bijective XCD swizzle (nwg=960, %8==0).
// ---------------------------------------------------------------------------
__global__ __launch_bounds__(512) void qkv_gemm(
    const unsigned short* __restrict__ A, const unsigned short* __restrict__ Bt,
    const float* __restrict__ bias,
    unsigned short* __restrict__ qw, unsigned short* __restrict__ kw,
    unsigned short* __restrict__ vtw) {
  __shared__ __attribute__((aligned(16))) unsigned short As[256 * 64];
  __shared__ __attribute__((aligned(16))) unsigned short Bs[128 * 64];
  const int t = threadIdx.x;
  const int lane = t & 63, w = t >> 6;             // w 0..7
  const int quad = lane >> 4, cl = lane & 15;
  // XCD-aware remap: dispatch-flat f runs work-item (f%8)*cpx + f/8
  const int nxb = gridDim.x;                       // 15
  const int flatb = blockIdx.y * nxb + blockIdx.x;
  const int cpx = (nxb * gridDim.y) >> 3;          // 120
  const int swz = (flatb & 7) * cpx + (flatb >> 3);
  const int m0 = (swz / nxb) * 256, n0 = (swz % nxb) * 128;
  const int wr = (w >> 1) * 64, wc = (w & 1) * 64; // wave grid 4(M) x 2(N)

  // staging: wave w stages A rows [w*32, w*32+32) (4 glds) and
  // B rows [w*16, w*16+16) (2 glds). Per-8-row source chunk swizzle
  // ((lane&7)^r8) — the R2-proven conflict-free pattern.
  const int r8 = lane >> 3;
  const int sw = ((lane & 7) ^ r8) * 8;
  const unsigned short* asrc = A + (size_t)(m0 + w * 32 + r8) * DIM + sw;
  const unsigned short* bsrc = Bt + (size_t)(n0 + w * 16 + r8) * DIM + sw;

  const int x = cl & 7;
  const int aoff0 = (wr + cl) * 64 + (quad ^ x) * 8;
  const int aoff1 = (wr + cl) * 64 + ((4 + quad) ^ x) * 8;
  const int boff0 = (wc + cl) * 64 + (quad ^ x) * 8;
  const int boff1 = (wc + cl) * 64 + ((4 + quad) ^ x) * 8;

  f32x4 acc[4][4];
#pragma unroll
  for (int i = 0; i < 4; ++i)
#pragma unroll
    for (int j = 0; j < 4; ++j) acc[i][j] = (f32x4){0.f, 0.f, 0.f, 0.f};

  for (int kt = 0; kt < DIM / 64; ++kt) {
    __syncthreads();
#pragma unroll
    for (int i = 0; i < 4; ++i)
      glds16(asrc + (size_t)i * 8 * DIM, &As[(w * 32 + i * 8) * 64]);
#pragma unroll
    for (int g = 0; g < 2; ++g)
      glds16(bsrc + (size_t)g * 8 * DIM, &Bs[(w * 16 + g * 8) * 64]);
    asrc += 64; bsrc += 64;
    __syncthreads();
#pragma unroll
    for (int ks = 0; ks < 2; ++ks) {
      const int ao = ks ? aoff1 : aoff0, bo = ks ? boff1 : boff0;
      bf16x8 af[4], bfr[4];
#pragma unroll
      for (int i = 0; i < 4; ++i) af[i] = *(const bf16x8*)&As[ao + i * 1024];
#pragma unroll
      for (int j = 0; j < 4; ++j) bfr[j] = *(const bf16x8*)&Bs[bo + j * 1024];
#pragma unroll
      for (int i = 0; i < 4; ++i)
#pragma unroll
        for (int j = 0; j < 4; ++j) acc[i][j] = mfma16(af[i], bfr[j], acc[i][j]);
    }
  }

  const int sec = n0 / DIM;  // 0=q, 1=k, 2=v (block-uniform)
  unsigned short* qk = (sec == 0) ? qw : kw;
  const float sc = (sec == 0) ? SM_C : 1.0f;  // fold softmax scale into Q
#pragma unroll
  for (int j = 0; j < 4; ++j) {
    int cc = n0 + wc + j * 16 + cl;
    int cr = cc - sec * DIM;
    int h = cr >> 6, d = cr & 63;
    float bv = bias[cc];
#pragma unroll
    for (int i = 0; i < 4; ++i) {
      int rbase = m0 + wr + i * 16 + quad * 4;
      int b = rbase >> 10, n = rbase & 1023;
      int bh = b * NHEADS + h;
      if (sec < 2) {
        size_t base = ((size_t)bh * SEQ + n) * HDIM + d;
#pragma unroll
        for (int r = 0; r < 4; ++r)
          qk[base + (size_t)r * HDIM] = f2b((acc[i][j][r] + bv) * sc);
      } else {
        ushort4 s;
        s.x = f2b(acc[i][j][0] + bv);
        s.y = f2b(acc[i][j][1] + bv);
        s.z = f2b(acc[i][j][2] + bv);
        s.w = f2b(acc[i][j][3] + bv);
        *(ushort4*)(vtw + ((size_t)bh * HDIM + d) * SEQ + n) = s;
      }
    }
  }
}

// ---------------------------------------------------------------------------
// K2: flash attention, no P LDS round-trip, full-rate K=32 PV.
// QBLK=256: each wave owns 64 q-rows (i=0..3). Rationale: every wave reads
// the FULL 16 KB K+V tile per kt regardless of q-rows owned, so q-rows/wave
// sets the LDS-reads-per-FLOP. 32->64 rows halves LDS read demand (~28us ->
// ~14us total) and halves staging traffic, at fixed MFMA/exp2 per FLOP.
// 3-buffer K/V rotation, depth-2 prefetch, counted vmcnt(4) + raw s_barrier
// (T4). LDS 48 KB; grid 640 = 160 bh x 4 qb, flat = bh + 160*qb (XCD-affine).
// ---------------------------------------------------------------------------
__global__ __launch_bounds__(256) void attn_kernel(
    const unsigned short* __restrict__ qw, const unsigned short* __restrict__ kw,
    const unsigned short* __restrict__ vtw, unsigned short* __restrict__ out) {
  __shared__ __attribute__((aligned(16))) unsigned short Ks[3][64 * 64];
  __shared__ __attribute__((aligned(16))) unsigned short Vs[3][64 * 64];
  const int t = threadIdx.x;
  const int lane = t & 63, w = t >> 6;
  const int quad = lane >> 4, cl = lane & 15;
  const int flat = blockIdx.x;
  const int bh = flat % NBH;     // flat % 8 == bh % 8 -> XCD affinity
  const int qb = flat / NBH;     // 0..3
  const size_t qkbase = (size_t)bh * SEQ * HDIM;
  const size_t vbase  = (size_t)bh * HDIM * SEQ;

  // staging sources (per-lane, swizzled); wave w stages LDS rows
  // [w*16, w*16+16). K source row is kv_remap'ed; V is identity.
  const int r8 = lane >> 3;
  const int sw = ((lane & 7) ^ r8) * 8;
  const int y0 = w * 16 + r8;       // LDS dest row, i=0 glds
  const int y1 = w * 16 + 8 + r8;   // LDS dest row, i=1 glds
  const unsigned short* ksrc0 = kw + qkbase + (size_t)kv_remap(y0) * HDIM + sw;
  const unsigned short* ksrc1 = kw + qkbase + (size_t)kv_remap(y1) * HDIM + sw;
  const unsigned short* vsrc  = vtw + vbase + (size_t)(w * 16 + r8) * SEQ + sw;

  // K fragment bases (b128, un-swizzling). Rows within a 16-row tile are cl;
  // tile pairs sit at +0 (A) / +1024 (B); 32-kv chunks at +2048*c.
  const int x = cl & 7;
  const int koff0 = cl * 64 + (quad ^ x) * 8;        // d 0..31
  const int koff1 = cl * 64 + ((4 + quad) ^ x) * 8;  // d 32..63

  // Q fragments (pre-scaled by SM_C in K1) — persistent, 64 rows/wave
  bf16x8 aq[4][2];
#pragma unroll
  for (int i = 0; i < 4; ++i) {
    const unsigned short* qp =
        qw + qkbase + (size_t)(qb * 256 + w * 64 + i * 16 + cl) * HDIM;
    aq[i][0] = *(const bf16x8*)(qp + quad * 8);
    aq[i][1] = *(const bf16x8*)(qp + 32 + quad * 8);
  }

  // bf16 1.0 x8 for ones-MFMA row sums
  union { unsigned short u[8]; bf16x8 v; } ow;
#pragma unroll
  for (int j = 0; j < 8; ++j) ow.u[j] = 0x3F80;
  const bf16x8 ones8 = ow.v;

  f32x4 o_acc[4][4];
#pragma unroll
  for (int i = 0; i < 4; ++i)
#pragma unroll
    for (int dt = 0; dt < 4; ++dt) o_acc[i][dt] = (f32x4){0.f, 0.f, 0.f, 0.f};
  f32x4 o1[4];                    // row sums (C-layout rows = quad*4+r)
#pragma unroll
  for (int i = 0; i < 4; ++i) o1[i] = (f32x4){0.f, 0.f, 0.f, 0.f};

  auto stageKV = [&](int b, int tile) {
    const unsigned short* kp0 = ksrc0 + (size_t)tile * 64 * HDIM;
    const unsigned short* kp1 = ksrc1 + (size_t)tile * 64 * HDIM;
    const unsigned short* vp  = vsrc + tile * 64;
    glds16(kp0,          &Ks[b][(w * 16) * 64]);
    glds16(kp1,          &Ks[b][(w * 16 + 8) * 64]);
    glds16(vp,           &Vs[b][(w * 16) * 64]);
    glds16(vp + 8 * SEQ, &Vs[b][(w * 16 + 8) * 64]);
  };

  // prologue: 2 tiles in flight (8 glds per wave)
  stageKV(0, 0);
  stageKV(1, 1);

  for (int kt = 0; kt < 16; ++kt) {
    // tile kt resident check: its 4 glds are the oldest; newest 4 (tile
    // kt+1) may stay in flight. Last iter has nothing newer -> vmcnt(0).
    if (kt < 15) asm volatile("s_waitcnt vmcnt(4)" ::: "memory");
    else         asm volatile("s_waitcnt vmcnt(0)" ::: "memory");
    __builtin_amdgcn_s_barrier();   // all waves see tile kt; buf (kt+2)%3 free

    if (kt + 2 < 16) stageKV((kt + 2) % 3, kt + 2);  // depth-2 prefetch

    const int cur = kt % 3;
    const unsigned short* Kc = &Ks[cur][0];
    const unsigned short* Vc = &Vs[cur][0];

    __builtin_amdgcn_s_setprio(1);   // favor compute waves over staging waves

    // S^T tile pairs per 32-kv chunk c: tile A rows = kv 8q+r, tile B rows =
    // kv 8q+4+r. exp2 + pack -> lane holds kv 8*quad..+7 for q-row cl:
    // a ready K=32 PV A-fragment. Row sums fold into the same fragment.
    bf16x8 pfr[4][2];              // [q-tile i][kv-chunk32 c]
#pragma unroll
    for (int c = 0; c < 2; ++c) {
      bf16x8 ka0 = *(const bf16x8*)&Kc[koff0 + c * 2048];
      bf16x8 ka1 = *(const bf16x8*)&Kc[koff1 + c * 2048];
      bf16x8 kb0 = *(const bf16x8*)&Kc[koff0 + c * 2048 + 1024];
      bf16x8 kb1 = *(const bf16x8*)&Kc[koff1 + c * 2048 + 1024];
#pragma unroll
      for (int i = 0; i < 4; ++i) {
        f32x4 zA = (f32x4){0.f, 0.f, 0.f, 0.f};
        zA = mfma16(ka0, aq[i][0], zA);   // A=K, B=Q -> S^T (kv 8q+r rows)
        zA = mfma16(ka1, aq[i][1], zA);
        f32x4 zB = (f32x4){0.f, 0.f, 0.f, 0.f};
        zB = mfma16(kb0, aq[i][0], zB);   // kv 8q+4+r rows
        zB = mfma16(kb1, aq[i][1], zB);
        union { unsigned short u[8]; bf16x8 v; } pk;
#pragma unroll
        for (int r = 0; r < 4; ++r) {
          pk.u[r]     = f2b(__builtin_amdgcn_exp2f(zA[r]));
          pk.u[4 + r] = f2b(__builtin_amdgcn_exp2f(zB[r]));
        }
        pfr[i][c] = pk.v;
        // row sums: D[q=quad*4+r][*] += P·1 (matches o_acc row layout)
        o1[i] = mfma16(pfr[i][c], ones8, o1[i]);
      }
    }

    // O += P V : B-frag = Vt[d=dt*16+cl][kv=32c+quad*8 .. +8] (b128 reads)
#pragma unroll
    for (int dt = 0; dt < 4; ++dt) {
      const int vrow = dt * 16 + cl;
      const int vx = vrow & 7;
#pragma unroll
      for (int c = 0; c < 2; ++c) {
        bf16x8 bv = *(const bf16x8*)&Vc[vrow * 64 + ((4 * c + quad) ^ vx) * 8];
#pragma unroll
        for (int i = 0; i < 4; ++i)
          o_acc[i][dt] = mfma16(pfr[i][c], bv, o_acc[i][dt]);
      }
    }

    __builtin_amdgcn_s_setprio(0);
  }

  // epilogue: o1 rows (quad*4+r) align with o_acc rows
  const int b = bh / NHEADS, h = bh % NHEADS;
#pragma unroll
  for (int i = 0; i < 4; ++i)
#pragma unroll
    for (int r = 0; r < 4; ++r) {
      float inv = 1.f / o1[i][r];
      int row = b * SEQ + qb * 256 + w * 64 + i * 16 + quad * 4 + r;
#pragma unroll
      for (int dt = 0; dt < 4; ++dt)
        out[(size_t)row * DIM + h * HDIM + dt * 16 + cl] =
            f2b(o_acc[i][dt][r] * inv);
    }
}

// ---------------------------------------------------------------------------
// K3: out = attn @ w_out + b_out. fp32 output. R2-exact structure: 128x128,
// BK=64, single-buffer 2-barrier, glds staging, conflict-free 128B-row
// swizzle. Bijective XCD swizzle (nwg=640, %8==0).
// ---------------------------------------------------------------------------
__global__ __launch_bounds__(256) void out_gemm(
    const unsigned short* __restrict__ A, const unsigned short* __restrict__ Bt,
    const float* __restrict__ bias, float* __restrict__ C) {
  __shared__ __attribute__((aligned(16))) unsigned short As[128 * 64];
  __shared__ __attribute__((aligned(16))) unsigned short Bs[128 * 64];
  const int t = threadIdx.x;
  const int lane = t & 63, w = t >> 6;
  const int quad = lane >> 4, cl = lane & 15;
  const int nxb = gridDim.x;                       // 5
  const int flatb = blockIdx.y * nxb + blockIdx.x;
  const int cpx = (nxb * gridDim.y) >> 3;          // 80
  const int swz = (flatb & 7) * cpx + (flatb >> 3);
  const int m0 = (swz / nxb) * 128, n0 = (swz % nxb) * 128;
  const int wr = (w >> 1) * 64, wc = (w & 1) * 64;

  const int r8 = lane >> 3;
  const int sw = ((lane & 7) ^ r8) * 8;
  const unsigned short* asrc = A + (size_t)(m0 + w * 32 + r8) * DIM + sw;
  const unsigned short* bsrc = Bt + (size_t)(n0 + w * 32 + r8) * DIM + sw;

  const int x = cl & 7;
  const int aoff0 = (wr + cl) * 64 + (quad ^ x) * 8;
  const int aoff1 = (wr + cl) * 64 + ((4 + quad) ^ x) * 8;
  const int boff0 = (wc + cl) * 64 + (quad ^ x) * 8;
  const int boff1 = (wc + cl) * 64 + ((4 + quad) ^ x) * 8;

  f32x4 acc[4][4];
#pragma unroll
  for (int i = 0; i < 4; ++i)
#pragma unroll
    for (int j = 0; j < 4; ++j) acc[i][j] = (f32x4){0.f, 0.f, 0.f, 0.f};

  for (int kt = 0; kt < DIM / 64; ++kt) {
    __syncthreads();
#pragma unroll
    for (int i = 0; i < 4; ++i) {
      glds16(asrc + (size_t)i * 8 * DIM, &As[(w * 32 + i * 8) * 64]);
      glds16(bsrc + (size_t)i * 8 * DIM, &Bs[(w * 32 + i * 8) * 64]);
    }
    asrc += 64; bsrc += 64;
    __syncthreads();
#pragma unroll
    for (int ks = 0; ks < 2; ++ks) {
      const int ao = ks ? aoff1 : aoff0, bo = ks ? boff1 : boff0;
      bf16x8 af[4], bfr[4];
#pragma unroll
      for (int i = 0; i < 4; ++i) af[i] = *(const bf16x8*)&As[ao + i * 1024];
#pragma unroll
      for (int j = 0; j < 4; ++j) bfr[j] = *(const bf16x8*)&Bs[bo + j * 1024];
#pragma unroll
      for (int i = 0; i < 4; ++i)
#pragma unroll
        for (int j = 0; j < 4; ++j) acc[i][j] = mfma16(af[i], bfr[j], acc[i][j]);
    }
  }
#pragma unroll
  for (int j = 0; j < 4; ++j) {
    int cc = n0 + wc + j * 16 + cl;
    float bv = bias[cc];
#pragma unroll
    for (int i = 0; i < 4; ++i) {
#pragma unroll
      for (int r = 0; r < 4; ++r) {
        int rr = m0 + wr + i * 16 + quad * 4 + r;
        C[(size_t)rr * DIM + cc] = acc[i][j][r] + bv;
      }
    }
  }
}

// ---------------------------------------------------------------------------
extern "C" void kernel_launch(void* const* d_in, const int* in_sizes, int n_in,
                              void* d_out, int out_size, void* d_ws, size_t ws_size,
                              hipStream_t stream) {
  const float* x     = (const float*)d_in[0];
  const float* w_qkv = (const float*)d_in[1];
  const float* b_qkv = (const float*)d_in[2];
  const float* w_out = (const float*)d_in[3];
  const float* b_out = (const float*)d_in[4];
  float* out = (float*)d_out;

  unsigned short* ws = (unsigned short*)d_ws;
  unsigned short* xb      = ws;                          // 10,485,760 (aliased w/ attn_ws)
  unsigned short* wt_qkv  = ws + 10485760;               // 1,228,800
  unsigned short* wt_out  = wt_qkv + 1228800;            // 409,600
  unsigned short* qw      = wt_out + 409600;             // 10,485,760
  unsigned short* kw      = qw + 10485760;               // 10,485,760
  unsigned short* vtw     = kw + 10485760;               // 10,485,760
  unsigned short* attn_ws = xb;                          // alias: xb dead after K1

  convert_x<<<MROWS * DIM / 1024, 256, 0, stream>>>(x, xb);
  transpose_w<<<dim3(QKVN / 32, DIM / 32), 256, 0, stream>>>(w_qkv, wt_qkv, DIM, QKVN);
  transpose_w<<<dim3(DIM / 32, DIM / 32), 256, 0, stream>>>(w_out, wt_out, DIM, DIM);
  // 256x128 tile, 8 waves: grid 15 x 64 = 960 blocks (%8==0)
  qkv_gemm<<<dim3(QKVN / 128, MROWS / 256), 512, 0, stream>>>(xb, wt_qkv, b_qkv, qw, kw, vtw);
  // flat = bh + 160*qb  (XCD-affine); QBLK=256 -> 640 blocks
  attn_kernel<<<dim3(NBH * (SEQ / 256)), 256, 0, stream>>>(qw, kw, vtw, attn_ws);
  out_gemm<<<dim3(DIM / 128, MROWS / 128), 256, 0, stream>>>(attn_ws, wt_out, b_out, out);
}

// Round 9
// 229.649 us; speedup vs baseline: 1.0261x; 1.0261x over previous
//
#include <hip/hip_runtime.h>

#define DIM 640
#define NHEADS 10
#define HDIM 64
#define SEQ 1024
#define BATCH 16
#define MROWS (BATCH * SEQ)   // 16384
#define QKVN (3 * DIM)        // 1920
#define NBH (BATCH * NHEADS)  // 160

typedef float f32x4 __attribute__((ext_vector_type(4)));
typedef __bf16 bf16x8 __attribute__((ext_vector_type(8)));

// 640^-0.5 * log2(e) — folded into Q at K1 epilogue
#define SM_C 0.057027536f

// hardware bf16 convert (v_cvt_pk_bf16_f32 on gfx950), RNE
__device__ __forceinline__ unsigned short f2b(float f) {
  union { __bf16 h; unsigned short u; } v;
  v.h = (__bf16)f;
  return v.u;
}

__device__ __forceinline__ f32x4 mfma16(bf16x8 a, bf16x8 b, f32x4 c) {
  return __builtin_amdgcn_mfma_f32_16x16x32_bf16(a, b, c, 0, 0, 0);
}

// async global->LDS, 16B per lane. dest base wave-uniform; lane i lands at
// dest + i*16B. XOR swizzle is encoded in the per-lane SOURCE address.
typedef __attribute__((address_space(3))) unsigned int as3_u32;
typedef const __attribute__((address_space(1))) unsigned int as1_u32;
__device__ __forceinline__ void glds16(const unsigned short* g, unsigned short* l) {
  __builtin_amdgcn_global_load_lds((as1_u32*)g, (as3_u32*)l, 16, 0, 0);
}

// kv row remap for K staging: LDS row y holds source kv row kv_remap(y).
// Within each 32-kv chunk: tile-A rows (y&31 < 16) hold kv 8Q+r (r<4),
// tile-B rows hold kv 8Q+r+4. After S^T = mfma(K,Q), lane 'quad' then holds
// kv = 8*quad + 0..7 for its q-row across the (A,B) tile pair — exactly the
// A-operand layout of the K=32 MFMA. PV runs at full rate, no cross-lane ops.
__device__ __forceinline__ int kv_remap(int y) {
  return 32 * (y >> 5) + 8 * ((y & 15) >> 2) + (y & 3) + 4 * ((y >> 4) & 1);
}

// ---------------------------------------------------------------------------
// K0a: x fp32 -> bf16, same layout.
// ---------------------------------------------------------------------------
__global__ __launch_bounds__(256) void convert_x(
    const float* __restrict__ X, unsigned short* __restrict__ xb) {
  int i = (blockIdx.x * 256 + threadIdx.x) * 4;
  float4 v = *(const float4*)(X + i);
  ushort4 s;
  s.x = f2b(v.x); s.y = f2b(v.y); s.z = f2b(v.z); s.w = f2b(v.w);
  *(ushort4*)(xb + i) = s;
}

// ---------------------------------------------------------------------------
// K0b: W fp32 [R][C] -> Wt bf16 [C][R] (transpose+convert).
// ---------------------------------------------------------------------------
__global__ __launch_bounds__(256) void transpose_w(
    const float* __restrict__ W, unsigned short* __restrict__ Wt, int R, int C) {
  __shared__ int tile[32][33];
  const int tx = threadIdx.x & 31, ty = threadIdx.x >> 5;   // ty 0..7
  const int c0 = blockIdx.x * 32, r0 = blockIdx.y * 32;
#pragma unroll
  for (int i = 0; i < 4; ++i)
    tile[ty + 8 * i][tx] = f2b(W[(r0 + ty + 8 * i) * C + c0 + tx]);
  __syncthreads();
#pragma unroll
  for (int i = 0; i < 4; ++i)
    Wt[(c0 + ty + 8 * i) * R + r0 + tx] = (unsigned short)tile[tx][ty + 8 * i];
}

// ---------------------------------------------------------------------------
// K1: qkv = xb @ w_qkv^T-staged + b. Scatters Q (pre-scaled by SM_C), K into
// [bh][n][64]; V into [bh][64][n] (pre-transposed).
// 256x128 tile, 8 waves (512 thr), BK=64, single-buffer 2-barrier K-loop.
// LDS 48KB: As 256x64 (32K) + Bs 128x64 (16K). Conflict-free 128B-row
// swizzle. Bijective XCD swizzle (nwg=960, %8==0).
// ---------------------------------------------------------------------------
__global__ __launch_bounds__(512) void qkv_gemm(
    const unsigned short* __restrict__ A, const unsigned short* __restrict__ Bt,
    const float* __restrict__ bias,
    unsigned short* __restrict__ qw, unsigned short* __restrict__ kw,
    unsigned short* __restrict__ vtw) {
  __shared__ __attribute__((aligned(16))) unsigned short As[256 * 64];
  __shared__ __attribute__((aligned(16))) unsigned short Bs[128 * 64];
  const int t = threadIdx.x;
  const int lane = t & 63, w = t >> 6;             // w 0..7
  const int quad = lane >> 4, cl = lane & 15;
  // XCD-aware remap: dispatch-flat f runs work-item (f%8)*cpx + f/8
  const int nxb = gridDim.x;                       // 15
  const int flatb = blockIdx.y * nxb + blockIdx.x;
  const int cpx = (nxb * gridDim.y) >> 3;          // 120
  const int swz = (flatb & 7) * cpx + (flatb >> 3);
  const int m0 = (swz / nxb) * 256, n0 = (swz % nxb) * 128;
  const int wr = (w >> 1) * 64, wc = (w & 1) * 64; // wave grid 4(M) x 2(N)

  // staging: wave w stages A rows [w*32, w*32+32) (4 glds) and
  // B rows [w*16, w*16+16) (2 glds). Per-8-row source chunk swizzle
  // ((lane&7)^r8) — the R2-proven conflict-free pattern.
  const int r8 = lane >> 3;
  const int sw = ((lane & 7) ^ r8) * 8;
  const unsigned short* asrc = A + (size_t)(m0 + w * 32 + r8) * DIM + sw;
  const unsigned short* bsrc = Bt + (size_t)(n0 + w * 16 + r8) * DIM + sw;

  const int x = cl & 7;
  const int aoff0 = (wr + cl) * 64 + (quad ^ x) * 8;
  const int aoff1 = (wr + cl) * 64 + ((4 + quad) ^ x) * 8;
  const int boff0 = (wc + cl) * 64 + (quad ^ x) * 8;
  const int boff1 = (wc + cl) * 64 + ((4 + quad) ^ x) * 8;

  f32x4 acc[4][4];
#pragma unroll
  for (int i = 0; i < 4; ++i)
#pragma unroll
    for (int j = 0; j < 4; ++j) acc[i][j] = (f32x4){0.f, 0.f, 0.f, 0.f};

  for (int kt = 0; kt < DIM / 64; ++kt) {
    __syncthreads();
#pragma unroll
    for (int i = 0; i < 4; ++i)
      glds16(asrc + (size_t)i * 8 * DIM, &As[(w * 32 + i * 8) * 64]);
#pragma unroll
    for (int g = 0; g < 2; ++g)
      glds16(bsrc + (size_t)g * 8 * DIM, &Bs[(w * 16 + g * 8) * 64]);
    asrc += 64; bsrc += 64;
    __syncthreads();
#pragma unroll
    for (int ks = 0; ks < 2; ++ks) {
      const int ao = ks ? aoff1 : aoff0, bo = ks ? boff1 : boff0;
      bf16x8 af[4], bfr[4];
#pragma unroll
      for (int i = 0; i < 4; ++i) af[i] = *(const bf16x8*)&As[ao + i * 1024];
#pragma unroll
      for (int j = 0; j < 4; ++j) bfr[j] = *(const bf16x8*)&Bs[bo + j * 1024];
#pragma unroll
      for (int i = 0; i < 4; ++i)
#pragma unroll
        for (int j = 0; j < 4; ++j) acc[i][j] = mfma16(af[i], bfr[j], acc[i][j]);
    }
  }

  const int sec = n0 / DIM;  // 0=q, 1=k, 2=v (block-uniform)
  unsigned short* qk = (sec == 0) ? qw : kw;
  const float sc = (sec == 0) ? SM_C : 1.0f;  // fold softmax scale into Q
#pragma unroll
  for (int j = 0; j < 4; ++j) {
    int cc = n0 + wc + j * 16 + cl;
    int cr = cc - sec * DIM;
    int h = cr >> 6, d = cr & 63;
    float bv = bias[cc];
#pragma unroll
    for (int i = 0; i < 4; ++i) {
      int rbase = m0 + wr + i * 16 + quad * 4;
      int b = rbase >> 10, n = rbase & 1023;
      int bh = b * NHEADS + h;
      if (sec < 2) {
        size_t base = ((size_t)bh * SEQ + n) * HDIM + d;
#pragma unroll
        for (int r = 0; r < 4; ++r)
          qk[base + (size_t)r * HDIM] = f2b((acc[i][j][r] + bv) * sc);
      } else {
        ushort4 s;
        s.x = f2b(acc[i][j][0] + bv);
        s.y = f2b(acc[i][j][1] + bv);
        s.z = f2b(acc[i][j][2] + bv);
        s.w = f2b(acc[i][j][3] + bv);
        *(ushort4*)(vtw + ((size_t)bh * HDIM + d) * SEQ + n) = s;
      }
    }
  }
}

// ---------------------------------------------------------------------------
// K2: flash attention, no P LDS round-trip, full-rate K=32 PV.
// 8 waves x 32 q-rows (QBLK=256, 512 thr): per-wave state identical to the
// proven 61us R6 kernel (i=2, aq[2][2], o_acc[2][4], ~72 VGPR) — R7 showed
// per-wave state growth (120 VGPR) collapses occupancy. Block-level
// amortization doubles instead: each 16KB K/V tile feeds 256 q-rows
// (staging traffic + barriers per q-row halve), 24-wave/CU residency cap.
// stageKV = 2 glds/wave (K rows w*8+r8 kv_remap'ed, V rows w*8+r8; both
// enumerate rows 0..63, (y&7)=r8 keeps the proven swizzle parity).
// 3-buffer rotation, depth-2 prefetch, counted vmcnt(2) + raw s_barrier.
// Grid 640 = 160 bh x 4 qb, flat = bh + 160*qb (XCD-affine).
// ---------------------------------------------------------------------------
__global__ __launch_bounds__(512) void attn_kernel(
    const unsigned short* __restrict__ qw, const unsigned short* __restrict__ kw,
    const unsigned short* __restrict__ vtw, unsigned short* __restrict__ out) {
  __shared__ __attribute__((aligned(16))) unsigned short Ks[3][64 * 64];
  __shared__ __attribute__((aligned(16))) unsigned short Vs[3][64 * 64];
  const int t = threadIdx.x;
  const int lane = t & 63, w = t >> 6;             // w 0..7
  const int quad = lane >> 4, cl = lane & 15;
  const int flat = blockIdx.x;
  const int bh = flat % NBH;     // flat % 8 == bh % 8 -> XCD affinity
  const int qb = flat / NBH;     // 0..3
  const size_t qkbase = (size_t)bh * SEQ * HDIM;
  const size_t vbase  = (size_t)bh * HDIM * SEQ;

  // staging sources (per-lane, swizzled); wave w stages LDS rows
  // [w*8, w*8+8) of K (kv_remap'ed) and V (identity). (y&7) == r8.
  const int r8 = lane >> 3;
  const int sw = ((lane & 7) ^ r8) * 8;
  const int y0 = w * 8 + r8;        // LDS dest row
  const unsigned short* ksrc0 = kw + qkbase + (size_t)kv_remap(y0) * HDIM + sw;
  const unsigned short* vsrc  = vtw + vbase + (size_t)(w * 8 + r8) * SEQ + sw;

  // K fragment bases (b128, un-swizzling). Rows within a 16-row tile are cl;
  // tile pairs sit at +0 (A) / +1024 (B); 32-kv chunks at +2048*c.
  const int x = cl & 7;
  const int koff0 = cl * 64 + (quad ^ x) * 8;        // d 0..31
  const int koff1 = cl * 64 + ((4 + quad) ^ x) * 8;  // d 32..63

  // Q fragments (pre-scaled by SM_C in K1) — persistent, 32 rows/wave
  bf16x8 aq[2][2];
#pragma unroll
  for (int i = 0; i < 2; ++i) {
    const unsigned short* qp =
        qw + qkbase + (size_t)(qb * 256 + w * 32 + i * 16 + cl) * HDIM;
    aq[i][0] = *(const bf16x8*)(qp + quad * 8);
    aq[i][1] = *(const bf16x8*)(qp + 32 + quad * 8);
  }

  // bf16 1.0 x8 for ones-MFMA row sums
  union { unsigned short u[8]; bf16x8 v; } ow;
#pragma unroll
  for (int j = 0; j < 8; ++j) ow.u[j] = 0x3F80;
  const bf16x8 ones8 = ow.v;

  f32x4 o_acc[2][4];
#pragma unroll
  for (int i = 0; i < 2; ++i)
#pragma unroll
    for (int dt = 0; dt < 4; ++dt) o_acc[i][dt] = (f32x4){0.f, 0.f, 0.f, 0.f};
  f32x4 o1[2];                    // row sums (C-layout rows = quad*4+r)
  o1[0] = (f32x4){0.f, 0.f, 0.f, 0.f};
  o1[1] = (f32x4){0.f, 0.f, 0.f, 0.f};

  auto stageKV = [&](int b, int tile) {   // 2 glds per wave
    glds16(ksrc0 + (size_t)tile * 64 * HDIM, &Ks[b][(w * 8) * 64]);
    glds16(vsrc + tile * 64,                 &Vs[b][(w * 8) * 64]);
  };

  // prologue: 2 tiles in flight (4 glds per wave)
  stageKV(0, 0);
  stageKV(1, 1);

  for (int kt = 0; kt < 16; ++kt) {
    // tile kt resident: its 2 glds are the oldest; newest 2 (tile kt+1)
    // may stay in flight. Last iter has nothing newer -> vmcnt(0).
    if (kt < 15) asm volatile("s_waitcnt vmcnt(2)" ::: "memory");
    else         asm volatile("s_waitcnt vmcnt(0)" ::: "memory");
    __builtin_amdgcn_s_barrier();   // all waves see tile kt; buf (kt+2)%3 free

    if (kt + 2 < 16) stageKV((kt + 2) % 3, kt + 2);  // depth-2 prefetch

    const int cur = kt % 3;
    const unsigned short* Kc = &Ks[cur][0];
    const unsigned short* Vc = &Vs[cur][0];

    __builtin_amdgcn_s_setprio(1);   // favor compute waves over staging waves

    // S^T tile pairs per 32-kv chunk c: tile A rows = kv 8q+r, tile B rows =
    // kv 8q+4+r. exp2 + pack -> lane holds kv 8*quad..+7 for q-row cl:
    // a ready K=32 PV A-fragment. Row sums fold into the same fragment.
    bf16x8 pfr[2][2];              // [q-tile i][kv-chunk32 c]
#pragma unroll
    for (int c = 0; c < 2; ++c) {
      bf16x8 ka0 = *(const bf16x8*)&Kc[koff0 + c * 2048];
      bf16x8 ka1 = *(const bf16x8*)&Kc[koff1 + c * 2048];
      bf16x8 kb0 = *(const bf16x8*)&Kc[koff0 + c * 2048 + 1024];
      bf16x8 kb1 = *(const bf16x8*)&Kc[koff1 + c * 2048 + 1024];
#pragma unroll
      for (int i = 0; i < 2; ++i) {
        f32x4 zA = (f32x4){0.f, 0.f, 0.f, 0.f};
        zA = mfma16(ka0, aq[i][0], zA);   // A=K, B=Q -> S^T (kv 8q+r rows)
        zA = mfma16(ka1, aq[i][1], zA);
        f32x4 zB = (f32x4){0.f, 0.f, 0.f, 0.f};
        zB = mfma16(kb0, aq[i][0], zB);   // kv 8q+4+r rows
        zB = mfma16(kb1, aq[i][1], zB);
        union { unsigned short u[8]; bf16x8 v; } pk;
#pragma unroll
        for (int r = 0; r < 4; ++r) {
          pk.u[r]     = f2b(__builtin_amdgcn_exp2f(zA[r]));
          pk.u[4 + r] = f2b(__builtin_amdgcn_exp2f(zB[r]));
        }
        pfr[i][c] = pk.v;
        // row sums: D[q=quad*4+r][*] += P·1 (matches o_acc row layout)
        o1[i] = mfma16(pfr[i][c], ones8, o1[i]);
      }
    }

    // O += P V : B-frag = Vt[d=dt*16+cl][kv=32c+quad*8 .. +8] (b128 reads)
#pragma unroll
    for (int dt = 0; dt < 4; ++dt) {
      const int vrow = dt * 16 + cl;
      const int vx = vrow & 7;
#pragma unroll
      for (int c = 0; c < 2; ++c) {
        bf16x8 bv = *(const bf16x8*)&Vc[vrow * 64 + ((4 * c + quad) ^ vx) * 8];
#pragma unroll
        for (int i = 0; i < 2; ++i)
          o_acc[i][dt] = mfma16(pfr[i][c], bv, o_acc[i][dt]);
      }
    }

    __builtin_amdgcn_s_setprio(0);
  }

  // epilogue: o1 rows (quad*4+r) align with o_acc rows
  const int b = bh / NHEADS, h = bh % NHEADS;
#pragma unroll
  for (int i = 0; i < 2; ++i)
#pragma unroll
    for (int r = 0; r < 4; ++r) {
      float inv = 1.f / o1[i][r];
      int row = b * SEQ + qb * 256 + w * 32 + i * 16 + quad * 4 + r;
#pragma unroll
      for (int dt = 0; dt < 4; ++dt)
        out[(size_t)row * DIM + h * HDIM + dt * 16 + cl] =
            f2b(o_acc[i][dt][r] * inv);
    }
}

// ---------------------------------------------------------------------------
// K3: out = attn @ w_out + b_out. fp32 output. R2-exact structure: 128x128,
// BK=64, single-buffer 2-barrier, glds staging, conflict-free 128B-row
// swizzle. Bijective XCD swizzle (nwg=640, %8==0).
// ---------------------------------------------------------------------------
__global__ __launch_bounds__(256) void out_gemm(
    const unsigned short* __restrict__ A, const unsigned short* __restrict__ Bt,
    const float* __restrict__ bias, float* __restrict__ C) {
  __shared__ __attribute__((aligned(16))) unsigned short As[128 * 64];
  __shared__ __attribute__((aligned(16))) unsigned short Bs[128 * 64];
  const int t = threadIdx.x;
  const int lane = t & 63, w = t >> 6;
  const int quad = lane >> 4, cl = lane & 15;
  const int nxb = gridDim.x;                       // 5
  const int flatb = blockIdx.y * nxb + blockIdx.x;
  const int cpx = (nxb * gridDim.y) >> 3;          // 80
  const int swz = (flatb & 7) * cpx + (flatb >> 3);
  const int m0 = (swz / nxb) * 128, n0 = (swz % nxb) * 128;
  const int wr = (w >> 1) * 64, wc = (w & 1) * 64;

  const int r8 = lane >> 3;
  const int sw = ((lane & 7) ^ r8) * 8;
  const unsigned short* asrc = A + (size_t)(m0 + w * 32 + r8) * DIM + sw;
  const unsigned short* bsrc = Bt + (size_t)(n0 + w * 32 + r8) * DIM + sw;

  const int x = cl & 7;
  const int aoff0 = (wr + cl) * 64 + (quad ^ x) * 8;
  const int aoff1 = (wr + cl) * 64 + ((4 + quad) ^ x) * 8;
  const int boff0 = (wc + cl) * 64 + (quad ^ x) * 8;
  const int boff1 = (wc + cl) * 64 + ((4 + quad) ^ x) * 8;

  f32x4 acc[4][4];
#pragma unroll
  for (int i = 0; i < 4; ++i)
#pragma unroll
    for (int j = 0; j < 4; ++j) acc[i][j] = (f32x4){0.f, 0.f, 0.f, 0.f};

  for (int kt = 0; kt < DIM / 64; ++kt) {
    __syncthreads();
#pragma unroll
    for (int i = 0; i < 4; ++i) {
      glds16(asrc + (size_t)i * 8 * DIM, &As[(w * 32 + i * 8) * 64]);
      glds16(bsrc + (size_t)i * 8 * DIM, &Bs[(w * 32 + i * 8) * 64]);
    }
    asrc += 64; bsrc += 64;
    __syncthreads();
#pragma unroll
    for (int ks = 0; ks < 2; ++ks) {
      const int ao = ks ? aoff1 : aoff0, bo = ks ? boff1 : boff0;
      bf16x8 af[4], bfr[4];
#pragma unroll
      for (int i = 0; i < 4; ++i) af[i] = *(const bf16x8*)&As[ao + i * 1024];
#pragma unroll
      for (int j = 0; j < 4; ++j) bfr[j] = *(const bf16x8*)&Bs[bo + j * 1024];
#pragma unroll
      for (int i = 0; i < 4; ++i)
#pragma unroll
        for (int j = 0; j < 4; ++j) acc[i][j] = mfma16(af[i], bfr[j], acc[i][j]);
    }
  }
#pragma unroll
  for (int j = 0; j < 4; ++j) {
    int cc = n0 + wc + j * 16 + cl;
    float bv = bias[cc];
#pragma unroll
    for (int i = 0; i < 4; ++i) {
#pragma unroll
      for (int r = 0; r < 4; ++r) {
        int rr = m0 + wr + i * 16 + quad * 4 + r;
        C[(size_t)rr * DIM + cc] = acc[i][j][r] + bv;
      }
    }
  }
}

// ---------------------------------------------------------------------------
extern "C" void kernel_launch(void* const* d_in, const int* in_sizes, int n_in,
                              void* d_out, int out_size, void* d_ws, size_t ws_size,
                              hipStream_t stream) {
  const float* x     = (const float*)d_in[0];
  const float* w_qkv = (const float*)d_in[1];
  const float* b_qkv = (const float*)d_in[2];
  const float* w_out = (const float*)d_in[3];
  const float* b_out = (const float*)d_in[4];
  float* out = (float*)d_out;

  unsigned short* ws = (unsigned short*)d_ws;
  unsigned short* xb      = ws;                          // 10,485,760 (aliased w/ attn_ws)
  unsigned short* wt_qkv  = ws + 10485760;               // 1,228,800
  unsigned short* wt_out  = wt_qkv + 1228800;            // 409,600
  unsigned short* qw      = wt_out + 409600;             // 10,485,760
  unsigned short* kw      = qw + 10485760;               // 10,485,760
  unsigned short* vtw     = kw + 10485760;               // 10,485,760
  unsigned short* attn_ws = xb;                          // alias: xb dead after K1

  convert_x<<<MROWS * DIM / 1024, 256, 0, stream>>>(x, xb);
  transpose_w<<<dim3(QKVN / 32, DIM / 32), 256, 0, stream>>>(w_qkv, wt_qkv, DIM, QKVN);
  transpose_w<<<dim3(DIM / 32, DIM / 32), 256, 0, stream>>>(w_out, wt_out, DIM, DIM);
  // 256x128 tile, 8 waves: grid 15 x 64 = 960 blocks (%8==0)
  qkv_gemm<<<dim3(QKVN / 128, MROWS / 256), 512, 0, stream>>>(xb, wt_qkv, b_qkv, qw, kw, vtw);
  // flat = bh + 160*qb (XCD-affine); QBLK=256, 8 waves -> 640 blocks x 512
  attn_kernel<<<dim3(NBH * (SEQ / 256)), 512, 0, stream>>>(qw, kw, vtw, attn_ws);
  out_gemm<<<dim3(DIM / 128, MROWS / 128), 256, 0, stream>>>(attn_ws, wt_out, b_out, out);
}

// Round 10
// 215.758 us; speedup vs baseline: 1.0921x; 1.0644x over previous
//
#include <hip/hip_runtime.h>

#define DIM 640
#define NHEADS 10
#define HDIM 64
#define SEQ 1024
#define BATCH 16
#define MROWS (BATCH * SEQ)   // 16384
#define QKVN (3 * DIM)        // 1920
#define NBH (BATCH * NHEADS)  // 160

typedef float f32x4 __attribute__((ext_vector_type(4)));
typedef __bf16 bf16x8 __attribute__((ext_vector_type(8)));

// 640^-0.5 * log2(e) — folded into Q at K1 epilogue
#define SM_C 0.057027536f

// hardware bf16 convert (v_cvt_pk_bf16_f32 on gfx950), RNE
__device__ __forceinline__ unsigned short f2b(float f) {
  union { __bf16 h; unsigned short u; } v;
  v.h = (__bf16)f;
  return v.u;
}

__device__ __forceinline__ f32x4 mfma16(bf16x8 a, bf16x8 b, f32x4 c) {
  return __builtin_amdgcn_mfma_f32_16x16x32_bf16(a, b, c, 0, 0, 0);
}

// async global->LDS, 16B per lane. dest base wave-uniform; lane i lands at
// dest + i*16B. XOR swizzle is encoded in the per-lane SOURCE address.
typedef __attribute__((address_space(3))) unsigned int as3_u32;
typedef const __attribute__((address_space(1))) unsigned int as1_u32;
__device__ __forceinline__ void glds16(const unsigned short* g, unsigned short* l) {
  __builtin_amdgcn_global_load_lds((as1_u32*)g, (as3_u32*)l, 16, 0, 0);
}

// kv row remap for K staging: LDS row y holds source kv row kv_remap(y).
// Within each 32-kv chunk: tile-A rows (y&31 < 16) hold kv 8Q+r (r<4),
// tile-B rows hold kv 8Q+r+4. After S^T = mfma(K,Q), lane 'quad' then holds
// kv = 8*quad + 0..7 for its q-row across the (A,B) tile pair — exactly the
// A-operand layout of the K=32 MFMA. PV runs at full rate, no cross-lane ops.
__device__ __forceinline__ int kv_remap(int y) {
  return 32 * (y >> 5) + 8 * ((y & 15) >> 2) + (y & 3) + 4 * ((y >> 4) & 1);
}

// ---------------------------------------------------------------------------
// K0: fused preprocessing — one launch instead of three.
//   blocks [0, 10240):          x fp32 -> bf16 (convert part)
//   blocks [10240, 11440):      w_qkv [640][1920] -> wt_qkv [1920][640] bf16
//   blocks [11440, 11840):      w_out [640][640]  -> wt_out [640][640]  bf16
// The three jobs are independent and memory-bound; fusing removes 2 launch
// gaps and lets the small transposes ride under the big convert.
// ---------------------------------------------------------------------------
#define CONV_BLOCKS (MROWS * DIM / 1024)   // 10240
#define TQKV_BX (QKVN / 32)                // 60
#define TQKV_BLOCKS (TQKV_BX * (DIM / 32)) // 1200
#define TOUT_BX (DIM / 32)                 // 20
__global__ __launch_bounds__(256) void prep(
    const float* __restrict__ X, unsigned short* __restrict__ xb,
    const float* __restrict__ Wq, unsigned short* __restrict__ Wtq,
    const float* __restrict__ Wo, unsigned short* __restrict__ Wto) {
  __shared__ int tile[32][33];
  const int bid = blockIdx.x;
  if (bid < CONV_BLOCKS) {                 // convert_x part
    int i = (bid * 256 + threadIdx.x) * 4;
    float4 v = *(const float4*)(X + i);
    ushort4 s;
    s.x = f2b(v.x); s.y = f2b(v.y); s.z = f2b(v.z); s.w = f2b(v.w);
    *(ushort4*)(xb + i) = s;
    return;                                // block-uniform exit, no barrier after
  }
  // transpose parts
  const float* W; unsigned short* Wt; int R, C, bx, by;
  if (bid < CONV_BLOCKS + TQKV_BLOCKS) {
    int b = bid - CONV_BLOCKS;
    bx = b % TQKV_BX; by = b / TQKV_BX; W = Wq; Wt = Wtq; R = DIM; C = QKVN;
  } else {
    int b = bid - CONV_BLOCKS - TQKV_BLOCKS;
    bx = b % TOUT_BX; by = b / TOUT_BX; W = Wo; Wt = Wto; R = DIM; C = DIM;
  }
  const int tx = threadIdx.x & 31, ty = threadIdx.x >> 5;   // ty 0..7
  const int c0 = bx * 32, r0 = by * 32;
#pragma unroll
  for (int i = 0; i < 4; ++i)
    tile[ty + 8 * i][tx] = f2b(W[(r0 + ty + 8 * i) * C + c0 + tx]);
  __syncthreads();
#pragma unroll
  for (int i = 0; i < 4; ++i)
    Wt[(c0 + ty + 8 * i) * R + r0 + tx] = (unsigned short)tile[tx][ty + 8 * i];
}

// ---------------------------------------------------------------------------
// K1: qkv = xb @ w_qkv^T-staged + b. Scatters Q (pre-scaled by SM_C), K into
// [bh][n][64]; V into [bh][64][n] (pre-transposed).
// 256x128 tile, 8 waves (512 thr), BK=64, single-buffer 2-barrier K-loop.
// LDS 48KB: As 256x64 (32K) + Bs 128x64 (16K). Conflict-free 128B-row
// swizzle. Bijective XCD swizzle (nwg=960, %8==0).
// ---------------------------------------------------------------------------
__global__ __launch_bounds__(512) void qkv_gemm(
    const unsigned short* __restrict__ A, const unsigned short* __restrict__ Bt,
    const float* __restrict__ bias,
    unsigned short* __restrict__ qw, unsigned short* __restrict__ kw,
    unsigned short* __restrict__ vtw) {
  __shared__ __attribute__((aligned(16))) unsigned short As[256 * 64];
  __shared__ __attribute__((aligned(16))) unsigned short Bs[128 * 64];
  const int t = threadIdx.x;
  const int lane = t & 63, w = t >> 6;             // w 0..7
  const int quad = lane >> 4, cl = lane & 15;
  // XCD-aware remap: dispatch-flat f runs work-item (f%8)*cpx + f/8
  const int nxb = gridDim.x;                       // 15
  const int flatb = blockIdx.y * nxb + blockIdx.x;
  const int cpx = (nxb * gridDim.y) >> 3;          // 120
  const int swz = (flatb & 7) * cpx + (flatb >> 3);
  const int m0 = (swz / nxb) * 256, n0 = (swz % nxb) * 128;
  const int wr = (w >> 1) * 64, wc = (w & 1) * 64; // wave grid 4(M) x 2(N)

  // staging: wave w stages A rows [w*32, w*32+32) (4 glds) and
  // B rows [w*16, w*16+16) (2 glds). Per-8-row source chunk swizzle
  // ((lane&7)^r8) — the R2-proven conflict-free pattern.
  const int r8 = lane >> 3;
  const int sw = ((lane & 7) ^ r8) * 8;
  const unsigned short* asrc = A + (size_t)(m0 + w * 32 + r8) * DIM + sw;
  const unsigned short* bsrc = Bt + (size_t)(n0 + w * 16 + r8) * DIM + sw;

  const int x = cl & 7;
  const int aoff0 = (wr + cl) * 64 + (quad ^ x) * 8;
  const int aoff1 = (wr + cl) * 64 + ((4 + quad) ^ x) * 8;
  const int boff0 = (wc + cl) * 64 + (quad ^ x) * 8;
  const int boff1 = (wc + cl) * 64 + ((4 + quad) ^ x) * 8;

  f32x4 acc[4][4];
#pragma unroll
  for (int i = 0; i < 4; ++i)
#pragma unroll
    for (int j = 0; j < 4; ++j) acc[i][j] = (f32x4){0.f, 0.f, 0.f, 0.f};

  for (int kt = 0; kt < DIM / 64; ++kt) {
    __syncthreads();
#pragma unroll
    for (int i = 0; i < 4; ++i)
      glds16(asrc + (size_t)i * 8 * DIM, &As[(w * 32 + i * 8) * 64]);
#pragma unroll
    for (int g = 0; g < 2; ++g)
      glds16(bsrc + (size_t)g * 8 * DIM, &Bs[(w * 16 + g * 8) * 64]);
    asrc += 64; bsrc += 64;
    __syncthreads();
#pragma unroll
    for (int ks = 0; ks < 2; ++ks) {
      const int ao = ks ? aoff1 : aoff0, bo = ks ? boff1 : boff0;
      bf16x8 af[4], bfr[4];
#pragma unroll
      for (int i = 0; i < 4; ++i) af[i] = *(const bf16x8*)&As[ao + i * 1024];
#pragma unroll
      for (int j = 0; j < 4; ++j) bfr[j] = *(const bf16x8*)&Bs[bo + j * 1024];
#pragma unroll
      for (int i = 0; i < 4; ++i)
#pragma unroll
        for (int j = 0; j < 4; ++j) acc[i][j] = mfma16(af[i], bfr[j], acc[i][j]);
    }
  }

  const int sec = n0 / DIM;  // 0=q, 1=k, 2=v (block-uniform)
  unsigned short* qk = (sec == 0) ? qw : kw;
  const float sc = (sec == 0) ? SM_C : 1.0f;  // fold softmax scale into Q
#pragma unroll
  for (int j = 0; j < 4; ++j) {
    int cc = n0 + wc + j * 16 + cl;
    int cr = cc - sec * DIM;
    int h = cr >> 6, d = cr & 63;
    float bv = bias[cc];
#pragma unroll
    for (int i = 0; i < 4; ++i) {
      int rbase = m0 + wr + i * 16 + quad * 4;
      int b = rbase >> 10, n = rbase & 1023;
      int bh = b * NHEADS + h;
      if (sec < 2) {
        size_t base = ((size_t)bh * SEQ + n) * HDIM + d;
#pragma unroll
        for (int r = 0; r < 4; ++r)
          qk[base + (size_t)r * HDIM] = f2b((acc[i][j][r] + bv) * sc);
      } else {
        ushort4 s;
        s.x = f2b(acc[i][j][0] + bv);
        s.y = f2b(acc[i][j][1] + bv);
        s.z = f2b(acc[i][j][2] + bv);
        s.w = f2b(acc[i][j][3] + bv);
        *(ushort4*)(vtw + ((size_t)bh * HDIM + d) * SEQ + n) = s;
      }
    }
  }
}

// ---------------------------------------------------------------------------
// K2: flash attention, no P LDS round-trip, full-rate K=32 PV.
// 8 waves x 32 q-rows (QBLK=256, 512 thr): per-wave state = the proven R6
// kernel (~60 VGPR); block-level amortization doubled (R8: 61 -> 57.5us).
// 3-buffer rotation, depth-2 prefetch, counted vmcnt(2) + raw s_barrier.
// Grid 640 = 160 bh x 4 qb, flat = bh + 160*qb (XCD-affine).
// ---------------------------------------------------------------------------
__global__ __launch_bounds__(512) void attn_kernel(
    const unsigned short* __restrict__ qw, const unsigned short* __restrict__ kw,
    const unsigned short* __restrict__ vtw, unsigned short* __restrict__ out) {
  __shared__ __attribute__((aligned(16))) unsigned short Ks[3][64 * 64];
  __shared__ __attribute__((aligned(16))) unsigned short Vs[3][64 * 64];
  const int t = threadIdx.x;
  const int lane = t & 63, w = t >> 6;             // w 0..7
  const int quad = lane >> 4, cl = lane & 15;
  const int flat = blockIdx.x;
  const int bh = flat % NBH;     // flat % 8 == bh % 8 -> XCD affinity
  const int qb = flat / NBH;     // 0..3
  const size_t qkbase = (size_t)bh * SEQ * HDIM;
  const size_t vbase  = (size_t)bh * HDIM * SEQ;

  // staging sources (per-lane, swizzled); wave w stages LDS rows
  // [w*8, w*8+8) of K (kv_remap'ed) and V (identity). (y&7) == r8.
  const int r8 = lane >> 3;
  const int sw = ((lane & 7) ^ r8) * 8;
  const int y0 = w * 8 + r8;        // LDS dest row
  const unsigned short* ksrc0 = kw + qkbase + (size_t)kv_remap(y0) * HDIM + sw;
  const unsigned short* vsrc  = vtw + vbase + (size_t)(w * 8 + r8) * SEQ + sw;

  // K fragment bases (b128, un-swizzling). Rows within a 16-row tile are cl;
  // tile pairs sit at +0 (A) / +1024 (B); 32-kv chunks at +2048*c.
  const int x = cl & 7;
  const int koff0 = cl * 64 + (quad ^ x) * 8;        // d 0..31
  const int koff1 = cl * 64 + ((4 + quad) ^ x) * 8;  // d 32..63

  // Q fragments (pre-scaled by SM_C in K1) — persistent, 32 rows/wave
  bf16x8 aq[2][2];
#pragma unroll
  for (int i = 0; i < 2; ++i) {
    const unsigned short* qp =
        qw + qkbase + (size_t)(qb * 256 + w * 32 + i * 16 + cl) * HDIM;
    aq[i][0] = *(const bf16x8*)(qp + quad * 8);
    aq[i][1] = *(const bf16x8*)(qp + 32 + quad * 8);
  }

  // bf16 1.0 x8 for ones-MFMA row sums
  union { unsigned short u[8]; bf16x8 v; } ow;
#pragma unroll
  for (int j = 0; j < 8; ++j) ow.u[j] = 0x3F80;
  const bf16x8 ones8 = ow.v;

  f32x4 o_acc[2][4];
#pragma unroll
  for (int i = 0; i < 2; ++i)
#pragma unroll
    for (int dt = 0; dt < 4; ++dt) o_acc[i][dt] = (f32x4){0.f, 0.f, 0.f, 0.f};
  f32x4 o1[2];                    // row sums (C-layout rows = quad*4+r)
  o1[0] = (f32x4){0.f, 0.f, 0.f, 0.f};
  o1[1] = (f32x4){0.f, 0.f, 0.f, 0.f};

  auto stageKV = [&](int b, int tile) {   // 2 glds per wave
    glds16(ksrc0 + (size_t)tile * 64 * HDIM, &Ks[b][(w * 8) * 64]);
    glds16(vsrc + tile * 64,                 &Vs[b][(w * 8) * 64]);
  };

  // prologue: 2 tiles in flight (4 glds per wave)
  stageKV(0, 0);
  stageKV(1, 1);

  for (int kt = 0; kt < 16; ++kt) {
    // tile kt resident: its 2 glds are the oldest; newest 2 (tile kt+1)
    // may stay in flight. Last iter has nothing newer -> vmcnt(0).
    if (kt < 15) asm volatile("s_waitcnt vmcnt(2)" ::: "memory");
    else         asm volatile("s_waitcnt vmcnt(0)" ::: "memory");
    __builtin_amdgcn_s_barrier();   // all waves see tile kt; buf (kt+2)%3 free

    if (kt + 2 < 16) stageKV((kt + 2) % 3, kt + 2);  // depth-2 prefetch

    const int cur = kt % 3;
    const unsigned short* Kc = &Ks[cur][0];
    const unsigned short* Vc = &Vs[cur][0];

    __builtin_amdgcn_s_setprio(1);   // favor compute waves over staging waves

    // S^T tile pairs per 32-kv chunk c: tile A rows = kv 8q+r, tile B rows =
    // kv 8q+4+r. exp2 + pack -> lane holds kv 8*quad..+7 for q-row cl:
    // a ready K=32 PV A-fragment. Row sums fold into the same fragment.
    bf16x8 pfr[2][2];              // [q-tile i][kv-chunk32 c]
#pragma unroll
    for (int c = 0; c < 2; ++c) {
      bf16x8 ka0 = *(const bf16x8*)&Kc[koff0 + c * 2048];
      bf16x8 ka1 = *(const bf16x8*)&Kc[koff1 + c * 2048];
      bf16x8 kb0 = *(const bf16x8*)&Kc[koff0 + c * 2048 + 1024];
      bf16x8 kb1 = *(const bf16x8*)&Kc[koff1 + c * 2048 + 1024];
#pragma unroll
      for (int i = 0; i < 2; ++i) {
        f32x4 zA = (f32x4){0.f, 0.f, 0.f, 0.f};
        zA = mfma16(ka0, aq[i][0], zA);   // A=K, B=Q -> S^T (kv 8q+r rows)
        zA = mfma16(ka1, aq[i][1], zA);
        f32x4 zB = (f32x4){0.f, 0.f, 0.f, 0.f};
        zB = mfma16(kb0, aq[i][0], zB);   // kv 8q+4+r rows
        zB = mfma16(kb1, aq[i][1], zB);
        union { unsigned short u[8]; bf16x8 v; } pk;
#pragma unroll
        for (int r = 0; r < 4; ++r) {
          pk.u[r]     = f2b(__builtin_amdgcn_exp2f(zA[r]));
          pk.u[4 + r] = f2b(__builtin_amdgcn_exp2f(zB[r]));
        }
        pfr[i][c] = pk.v;
        // row sums: D[q=quad*4+r][*] += P·1 (matches o_acc row layout)
        o1[i] = mfma16(pfr[i][c], ones8, o1[i]);
      }
    }

    // O += P V : B-frag = Vt[d=dt*16+cl][kv=32c+quad*8 .. +8] (b128 reads)
#pragma unroll
    for (int dt = 0; dt < 4; ++dt) {
      const int vrow = dt * 16 + cl;
      const int vx = vrow & 7;
#pragma unroll
      for (int c = 0; c < 2; ++c) {
        bf16x8 bv = *(const bf16x8*)&Vc[vrow * 64 + ((4 * c + quad) ^ vx) * 8];
#pragma unroll
        for (int i = 0; i < 2; ++i)
          o_acc[i][dt] = mfma16(pfr[i][c], bv, o_acc[i][dt]);
      }
    }

    __builtin_amdgcn_s_setprio(0);
  }

  // epilogue: o1 rows (quad*4+r) align with o_acc rows
  const int b = bh / NHEADS, h = bh % NHEADS;
#pragma unroll
  for (int i = 0; i < 2; ++i)
#pragma unroll
    for (int r = 0; r < 4; ++r) {
      float inv = 1.f / o1[i][r];
      int row = b * SEQ + qb * 256 + w * 32 + i * 16 + quad * 4 + r;
#pragma unroll
      for (int dt = 0; dt < 4; ++dt)
        out[(size_t)row * DIM + h * HDIM + dt * 16 + cl] =
            f2b(o_acc[i][dt][r] * inv);
    }
}

// ---------------------------------------------------------------------------
// K3: out = attn @ w_out + b_out. fp32 output. 256x128 tile, 8 waves, BK=64,
// single-buffer 2-barrier K-loop (R6-proven qkv structure; per-block
// overhead halves vs 128x128). Grid 5 x 64 = 320 (%8==0), bijective XCD
// swizzle, cpx=40. LDS 48KB.
// ---------------------------------------------------------------------------
__global__ __launch_bounds__(512) void out_gemm(
    const unsigned short* __restrict__ A, const unsigned short* __restrict__ Bt,
    const float* __restrict__ bias, float* __restrict__ C) {
  __shared__ __attribute__((aligned(16))) unsigned short As[256 * 64];
  __shared__ __attribute__((aligned(16))) unsigned short Bs[128 * 64];
  const int t = threadIdx.x;
  const int lane = t & 63, w = t >> 6;             // w 0..7
  const int quad = lane >> 4, cl = lane & 15;
  const int nxb = gridDim.x;                       // 5
  const int flatb = blockIdx.y * nxb + blockIdx.x;
  const int cpx = (nxb * gridDim.y) >> 3;          // 40
  const int swz = (flatb & 7) * cpx + (flatb >> 3);
  const int m0 = (swz / nxb) * 256, n0 = (swz % nxb) * 128;
  const int wr = (w >> 1) * 64, wc = (w & 1) * 64;

  const int r8 = lane >> 3;
  const int sw = ((lane & 7) ^ r8) * 8;
  const unsigned short* asrc = A + (size_t)(m0 + w * 32 + r8) * DIM + sw;
  const unsigned short* bsrc = Bt + (size_t)(n0 + w * 16 + r8) * DIM + sw;

  const int x = cl & 7;
  const int aoff0 = (wr + cl) * 64 + (quad ^ x) * 8;
  const int aoff1 = (wr + cl) * 64 + ((4 + quad) ^ x) * 8;
  const int boff0 = (wc + cl) * 64 + (quad ^ x) * 8;
  const int boff1 = (wc + cl) * 64 + ((4 + quad) ^ x) * 8;

  f32x4 acc[4][4];
#pragma unroll
  for (int i = 0; i < 4; ++i)
#pragma unroll
    for (int j = 0; j < 4; ++j) acc[i][j] = (f32x4){0.f, 0.f, 0.f, 0.f};

  for (int kt = 0; kt < DIM / 64; ++kt) {
    __syncthreads();
#pragma unroll
    for (int i = 0; i < 4; ++i)
      glds16(asrc + (size_t)i * 8 * DIM, &As[(w * 32 + i * 8) * 64]);
#pragma unroll
    for (int g = 0; g < 2; ++g)
      glds16(bsrc + (size_t)g * 8 * DIM, &Bs[(w * 16 + g * 8) * 64]);
    asrc += 64; bsrc += 64;
    __syncthreads();
#pragma unroll
    for (int ks = 0; ks < 2; ++ks) {
      const int ao = ks ? aoff1 : aoff0, bo = ks ? boff1 : boff0;
      bf16x8 af[4], bfr[4];
#pragma unroll
      for (int i = 0; i < 4; ++i) af[i] = *(const bf16x8*)&As[ao + i * 1024];
#pragma unroll
      for (int j = 0; j < 4; ++j) bfr[j] = *(const bf16x8*)&Bs[bo + j * 1024];
#pragma unroll
      for (int i = 0; i < 4; ++i)
#pragma unroll
        for (int j = 0; j < 4; ++j) acc[i][j] = mfma16(af[i], bfr[j], acc[i][j]);
    }
  }
#pragma unroll
  for (int j = 0; j < 4; ++j) {
    int cc = n0 + wc + j * 16 + cl;
    float bv = bias[cc];
#pragma unroll
    for (int i = 0; i < 4; ++i) {
#pragma unroll
      for (int r = 0; r < 4; ++r) {
        int rr = m0 + wr + i * 16 + quad * 4 + r;
        C[(size_t)rr * DIM + cc] = acc[i][j][r] + bv;
      }
    }
  }
}

// ---------------------------------------------------------------------------
extern "C" void kernel_launch(void* const* d_in, const int* in_sizes, int n_in,
                              void* d_out, int out_size, void* d_ws, size_t ws_size,
                              hipStream_t stream) {
  const float* x     = (const float*)d_in[0];
  const float* w_qkv = (const float*)d_in[1];
  const float* b_qkv = (const float*)d_in[2];
  const float* w_out = (const float*)d_in[3];
  const float* b_out = (const float*)d_in[4];
  float* out = (float*)d_out;

  unsigned short* ws = (unsigned short*)d_ws;
  unsigned short* xb      = ws;                          // 10,485,760 (aliased w/ attn_ws)
  unsigned short* wt_qkv  = ws + 10485760;               // 1,228,800
  unsigned short* wt_out  = wt_qkv + 1228800;            // 409,600
  unsigned short* qw      = wt_out + 409600;             // 10,485,760
  unsigned short* kw      = qw + 10485760;               // 10,485,760
  unsigned short* vtw     = kw + 10485760;               // 10,485,760
  unsigned short* attn_ws = xb;                          // alias: xb dead after K1

  // fused preprocessing: convert + both weight transposes in one launch
  prep<<<CONV_BLOCKS + TQKV_BLOCKS + TOUT_BX * (DIM / 32), 256, 0, stream>>>(
      x, xb, w_qkv, wt_qkv, w_out, wt_out);
  // 256x128 tile, 8 waves: grid 15 x 64 = 960 blocks (%8==0)
  qkv_gemm<<<dim3(QKVN / 128, MROWS / 256), 512, 0, stream>>>(xb, wt_qkv, b_qkv, qw, kw, vtw);
  // flat = bh + 160*qb (XCD-affine); QBLK=256, 8 waves -> 640 blocks x 512
  attn_kernel<<<dim3(NBH * (SEQ / 256)), 512, 0, stream>>>(qw, kw, vtw, attn_ws);
  // 256x128 tile, 8 waves: grid 5 x 64 = 320 blocks (%8==0)
  out_gemm<<<dim3(DIM / 128, MROWS / 256), 512, 0, stream>>>(attn_ws, wt_out, b_out, out);
}

// Round 11
// 213.985 us; speedup vs baseline: 1.1012x; 1.0083x over previous
//
#include <hip/hip_runtime.h>

#define DIM 640
#define NHEADS 10
#define HDIM 64
#define SEQ 1024
#define BATCH 16
#define MROWS (BATCH * SEQ)   // 16384
#define QKVN (3 * DIM)        // 1920
#define NBH (BATCH * NHEADS)  // 160

typedef float f32x4 __attribute__((ext_vector_type(4)));
typedef __bf16 bf16x8 __attribute__((ext_vector_type(8)));

// 640^-0.5 * log2(e) — folded into Q at K1 epilogue
#define SM_C 0.057027536f

// hardware bf16 convert (v_cvt_pk_bf16_f32 on gfx950), RNE
__device__ __forceinline__ unsigned short f2b(float f) {
  union { __bf16 h; unsigned short u; } v;
  v.h = (__bf16)f;
  return v.u;
}

__device__ __forceinline__ f32x4 mfma16(bf16x8 a, bf16x8 b, f32x4 c) {
  return __builtin_amdgcn_mfma_f32_16x16x32_bf16(a, b, c, 0, 0, 0);
}

// async global->LDS, 16B per lane. dest base wave-uniform; lane i lands at
// dest + i*16B. XOR swizzle is encoded in the per-lane SOURCE address.
typedef __attribute__((address_space(3))) unsigned int as3_u32;
typedef const __attribute__((address_space(1))) unsigned int as1_u32;
__device__ __forceinline__ void glds16(const unsigned short* g, unsigned short* l) {
  __builtin_amdgcn_global_load_lds((as1_u32*)g, (as3_u32*)l, 16, 0, 0);
}

// kv row remap for K staging: LDS row y holds source kv row kv_remap(y).
// Within each 32-kv chunk: tile-A rows (y&31 < 16) hold kv 8Q+r (r<4),
// tile-B rows hold kv 8Q+r+4. After S^T = mfma(K,Q), lane 'quad' then holds
// kv = 8*quad + 0..7 for its q-row across the (A,B) tile pair — exactly the
// A-operand layout of the K=32 MFMA. PV runs at full rate, no cross-lane ops.
__device__ __forceinline__ int kv_remap(int y) {
  return 32 * (y >> 5) + 8 * ((y & 15) >> 2) + (y & 3) + 4 * ((y >> 4) & 1);
}

// ---------------------------------------------------------------------------
// K0: fused preprocessing — one launch instead of three.
//   blocks [0, 10240):          x fp32 -> bf16 (convert part)
//   blocks [10240, 11440):      w_qkv [640][1920] -> wt_qkv [1920][640] bf16
//   blocks [11440, 11840):      w_out [640][640]  -> wt_out [640][640]  bf16
// ---------------------------------------------------------------------------
#define CONV_BLOCKS (MROWS * DIM / 1024)   // 10240
#define TQKV_BX (QKVN / 32)                // 60
#define TQKV_BLOCKS (TQKV_BX * (DIM / 32)) // 1200
#define TOUT_BX (DIM / 32)                 // 20
__global__ __launch_bounds__(256) void prep(
    const float* __restrict__ X, unsigned short* __restrict__ xb,
    const float* __restrict__ Wq, unsigned short* __restrict__ Wtq,
    const float* __restrict__ Wo, unsigned short* __restrict__ Wto) {
  __shared__ int tile[32][33];
  const int bid = blockIdx.x;
  if (bid < CONV_BLOCKS) {                 // convert_x part
    int i = (bid * 256 + threadIdx.x) * 4;
    float4 v = *(const float4*)(X + i);
    ushort4 s;
    s.x = f2b(v.x); s.y = f2b(v.y); s.z = f2b(v.z); s.w = f2b(v.w);
    *(ushort4*)(xb + i) = s;
    return;                                // block-uniform exit, no barrier after
  }
  // transpose parts
  const float* W; unsigned short* Wt; int R, C, bx, by;
  if (bid < CONV_BLOCKS + TQKV_BLOCKS) {
    int b = bid - CONV_BLOCKS;
    bx = b % TQKV_BX; by = b / TQKV_BX; W = Wq; Wt = Wtq; R = DIM; C = QKVN;
  } else {
    int b = bid - CONV_BLOCKS - TQKV_BLOCKS;
    bx = b % TOUT_BX; by = b / TOUT_BX; W = Wo; Wt = Wto; R = DIM; C = DIM;
  }
  const int tx = threadIdx.x & 31, ty = threadIdx.x >> 5;   // ty 0..7
  const int c0 = bx * 32, r0 = by * 32;
#pragma unroll
  for (int i = 0; i < 4; ++i)
    tile[ty + 8 * i][tx] = f2b(W[(r0 + ty + 8 * i) * C + c0 + tx]);
  __syncthreads();
#pragma unroll
  for (int i = 0; i < 4; ++i)
    Wt[(c0 + ty + 8 * i) * R + r0 + tx] = (unsigned short)tile[tx][ty + 8 * i];
}

// ---------------------------------------------------------------------------
// K1: qkv = xb @ w_qkv^T-staged + b. Scatters Q (pre-scaled by SM_C), K into
// [bh][n][64]; V into [bh][64][n] (pre-transposed).
// 256x128 tile, 8 waves (512 thr), BK=64, single-buffer 2-barrier K-loop.
// LDS 48KB: As 256x64 (32K) + Bs 128x64 (16K). Conflict-free 128B-row
// swizzle. Bijective XCD swizzle (nwg=960, %8==0).
// ---------------------------------------------------------------------------
__global__ __launch_bounds__(512) void qkv_gemm(
    const unsigned short* __restrict__ A, const unsigned short* __restrict__ Bt,
    const float* __restrict__ bias,
    unsigned short* __restrict__ qw, unsigned short* __restrict__ kw,
    unsigned short* __restrict__ vtw) {
  __shared__ __attribute__((aligned(16))) unsigned short As[256 * 64];
  __shared__ __attribute__((aligned(16))) unsigned short Bs[128 * 64];
  const int t = threadIdx.x;
  const int lane = t & 63, w = t >> 6;             // w 0..7
  const int quad = lane >> 4, cl = lane & 15;
  // XCD-aware remap: dispatch-flat f runs work-item (f%8)*cpx + f/8
  const int nxb = gridDim.x;                       // 15
  const int flatb = blockIdx.y * nxb + blockIdx.x;
  const int cpx = (nxb * gridDim.y) >> 3;          // 120
  const int swz = (flatb & 7) * cpx + (flatb >> 3);
  const int m0 = (swz / nxb) * 256, n0 = (swz % nxb) * 128;
  const int wr = (w >> 1) * 64, wc = (w & 1) * 64; // wave grid 4(M) x 2(N)

  // staging: wave w stages A rows [w*32, w*32+32) (4 glds) and
  // B rows [w*16, w*16+16) (2 glds). Per-8-row source chunk swizzle
  // ((lane&7)^r8) — the R2-proven conflict-free pattern.
  const int r8 = lane >> 3;
  const int sw = ((lane & 7) ^ r8) * 8;
  const unsigned short* asrc = A + (size_t)(m0 + w * 32 + r8) * DIM + sw;
  const unsigned short* bsrc = Bt + (size_t)(n0 + w * 16 + r8) * DIM + sw;

  const int x = cl & 7;
  const int aoff0 = (wr + cl) * 64 + (quad ^ x) * 8;
  const int aoff1 = (wr + cl) * 64 + ((4 + quad) ^ x) * 8;
  const int boff0 = (wc + cl) * 64 + (quad ^ x) * 8;
  const int boff1 = (wc + cl) * 64 + ((4 + quad) ^ x) * 8;

  f32x4 acc[4][4];
#pragma unroll
  for (int i = 0; i < 4; ++i)
#pragma unroll
    for (int j = 0; j < 4; ++j) acc[i][j] = (f32x4){0.f, 0.f, 0.f, 0.f};

  for (int kt = 0; kt < DIM / 64; ++kt) {
    __syncthreads();
#pragma unroll
    for (int i = 0; i < 4; ++i)
      glds16(asrc + (size_t)i * 8 * DIM, &As[(w * 32 + i * 8) * 64]);
#pragma unroll
    for (int g = 0; g < 2; ++g)
      glds16(bsrc + (size_t)g * 8 * DIM, &Bs[(w * 16 + g * 8) * 64]);
    asrc += 64; bsrc += 64;
    __syncthreads();
#pragma unroll
    for (int ks = 0; ks < 2; ++ks) {
      const int ao = ks ? aoff1 : aoff0, bo = ks ? boff1 : boff0;
      bf16x8 af[4], bfr[4];
#pragma unroll
      for (int i = 0; i < 4; ++i) af[i] = *(const bf16x8*)&As[ao + i * 1024];
#pragma unroll
      for (int j = 0; j < 4; ++j) bfr[j] = *(const bf16x8*)&Bs[bo + j * 1024];
#pragma unroll
      for (int i = 0; i < 4; ++i)
#pragma unroll
        for (int j = 0; j < 4; ++j) acc[i][j] = mfma16(af[i], bfr[j], acc[i][j]);
    }
  }

  const int sec = n0 / DIM;  // 0=q, 1=k, 2=v (block-uniform)
  unsigned short* qk = (sec == 0) ? qw : kw;
  const float sc = (sec == 0) ? SM_C : 1.0f;  // fold softmax scale into Q
#pragma unroll
  for (int j = 0; j < 4; ++j) {
    int cc = n0 + wc + j * 16 + cl;
    int cr = cc - sec * DIM;
    int h = cr >> 6, d = cr & 63;
    float bv = bias[cc];
#pragma unroll
    for (int i = 0; i < 4; ++i) {
      int rbase = m0 + wr + i * 16 + quad * 4;
      int b = rbase >> 10, n = rbase & 1023;
      int bh = b * NHEADS + h;
      if (sec < 2) {
        size_t base = ((size_t)bh * SEQ + n) * HDIM + d;
#pragma unroll
        for (int r = 0; r < 4; ++r)
          qk[base + (size_t)r * HDIM] = f2b((acc[i][j][r] + bv) * sc);
      } else {
        ushort4 s;
        s.x = f2b(acc[i][j][0] + bv);
        s.y = f2b(acc[i][j][1] + bv);
        s.z = f2b(acc[i][j][2] + bv);
        s.w = f2b(acc[i][j][3] + bv);
        *(ushort4*)(vtw + ((size_t)bh * HDIM + d) * SEQ + n) = s;
      }
    }
  }
}

// ---------------------------------------------------------------------------
// K2: flash attention, no P LDS round-trip, full-rate K=32 PV.
// 8 waves x 32 q-rows (QBLK=256, 512 thr): per-wave state = the proven R6
// kernel (~60 VGPR); block-level amortization doubled (R8: 61 -> 57.5us).
// 3-buffer rotation, depth-2 prefetch, counted vmcnt(2) + raw s_barrier.
// Grid 640 = 160 bh x 4 qb, flat = bh + 160*qb (XCD-affine).
// ---------------------------------------------------------------------------
__global__ __launch_bounds__(512) void attn_kernel(
    const unsigned short* __restrict__ qw, const unsigned short* __restrict__ kw,
    const unsigned short* __restrict__ vtw, unsigned short* __restrict__ out) {
  __shared__ __attribute__((aligned(16))) unsigned short Ks[3][64 * 64];
  __shared__ __attribute__((aligned(16))) unsigned short Vs[3][64 * 64];
  const int t = threadIdx.x;
  const int lane = t & 63, w = t >> 6;             // w 0..7
  const int quad = lane >> 4, cl = lane & 15;
  const int flat = blockIdx.x;
  const int bh = flat % NBH;     // flat % 8 == bh % 8 -> XCD affinity
  const int qb = flat / NBH;     // 0..3
  const size_t qkbase = (size_t)bh * SEQ * HDIM;
  const size_t vbase  = (size_t)bh * HDIM * SEQ;

  // staging sources (per-lane, swizzled); wave w stages LDS rows
  // [w*8, w*8+8) of K (kv_remap'ed) and V (identity). (y&7) == r8.
  const int r8 = lane >> 3;
  const int sw = ((lane & 7) ^ r8) * 8;
  const int y0 = w * 8 + r8;        // LDS dest row
  const unsigned short* ksrc0 = kw + qkbase + (size_t)kv_remap(y0) * HDIM + sw;
  const unsigned short* vsrc  = vtw + vbase + (size_t)(w * 8 + r8) * SEQ + sw;

  // K fragment bases (b128, un-swizzling). Rows within a 16-row tile are cl;
  // tile pairs sit at +0 (A) / +1024 (B); 32-kv chunks at +2048*c.
  const int x = cl & 7;
  const int koff0 = cl * 64 + (quad ^ x) * 8;        // d 0..31
  const int koff1 = cl * 64 + ((4 + quad) ^ x) * 8;  // d 32..63

  // Q fragments (pre-scaled by SM_C in K1) — persistent, 32 rows/wave
  bf16x8 aq[2][2];
#pragma unroll
  for (int i = 0; i < 2; ++i) {
    const unsigned short* qp =
        qw + qkbase + (size_t)(qb * 256 + w * 32 + i * 16 + cl) * HDIM;
    aq[i][0] = *(const bf16x8*)(qp + quad * 8);
    aq[i][1] = *(const bf16x8*)(qp + 32 + quad * 8);
  }

  // bf16 1.0 x8 for ones-MFMA row sums
  union { unsigned short u[8]; bf16x8 v; } ow;
#pragma unroll
  for (int j = 0; j < 8; ++j) ow.u[j] = 0x3F80;
  const bf16x8 ones8 = ow.v;

  f32x4 o_acc[2][4];
#pragma unroll
  for (int i = 0; i < 2; ++i)
#pragma unroll
    for (int dt = 0; dt < 4; ++dt) o_acc[i][dt] = (f32x4){0.f, 0.f, 0.f, 0.f};
  f32x4 o1[2];                    // row sums (C-layout rows = quad*4+r)
  o1[0] = (f32x4){0.f, 0.f, 0.f, 0.f};
  o1[1] = (f32x4){0.f, 0.f, 0.f, 0.f};

  auto stageKV = [&](int b, int tile) {   // 2 glds per wave
    glds16(ksrc0 + (size_t)tile * 64 * HDIM, &Ks[b][(w * 8) * 64]);
    glds16(vsrc + tile * 64,                 &Vs[b][(w * 8) * 64]);
  };

  // prologue: 2 tiles in flight (4 glds per wave)
  stageKV(0, 0);
  stageKV(1, 1);

  for (int kt = 0; kt < 16; ++kt) {
    // tile kt resident: its 2 glds are the oldest; newest 2 (tile kt+1)
    // may stay in flight. Last iter has nothing newer -> vmcnt(0).
    if (kt < 15) asm volatile("s_waitcnt vmcnt(2)" ::: "memory");
    else         asm volatile("s_waitcnt vmcnt(0)" ::: "memory");
    __builtin_amdgcn_s_barrier();   // all waves see tile kt; buf (kt+2)%3 free

    if (kt + 2 < 16) stageKV((kt + 2) % 3, kt + 2);  // depth-2 prefetch

    const int cur = kt % 3;
    const unsigned short* Kc = &Ks[cur][0];
    const unsigned short* Vc = &Vs[cur][0];

    __builtin_amdgcn_s_setprio(1);   // favor compute waves over staging waves

    // S^T tile pairs per 32-kv chunk c: tile A rows = kv 8q+r, tile B rows =
    // kv 8q+4+r. exp2 + pack -> lane holds kv 8*quad..+7 for q-row cl:
    // a ready K=32 PV A-fragment. Row sums fold into the same fragment.
    bf16x8 pfr[2][2];              // [q-tile i][kv-chunk32 c]
#pragma unroll
    for (int c = 0; c < 2; ++c) {
      bf16x8 ka0 = *(const bf16x8*)&Kc[koff0 + c * 2048];
      bf16x8 ka1 = *(const bf16x8*)&Kc[koff1 + c * 2048];
      bf16x8 kb0 = *(const bf16x8*)&Kc[koff0 + c * 2048 + 1024];
      bf16x8 kb1 = *(const bf16x8*)&Kc[koff1 + c * 2048 + 1024];
#pragma unroll
      for (int i = 0; i < 2; ++i) {
        f32x4 zA = (f32x4){0.f, 0.f, 0.f, 0.f};
        zA = mfma16(ka0, aq[i][0], zA);   // A=K, B=Q -> S^T (kv 8q+r rows)
        zA = mfma16(ka1, aq[i][1], zA);
        f32x4 zB = (f32x4){0.f, 0.f, 0.f, 0.f};
        zB = mfma16(kb0, aq[i][0], zB);   // kv 8q+4+r rows
        zB = mfma16(kb1, aq[i][1], zB);
        union { unsigned short u[8]; bf16x8 v; } pk;
#pragma unroll
        for (int r = 0; r < 4; ++r) {
          pk.u[r]     = f2b(__builtin_amdgcn_exp2f(zA[r]));
          pk.u[4 + r] = f2b(__builtin_amdgcn_exp2f(zB[r]));
        }
        pfr[i][c] = pk.v;
        // row sums: D[q=quad*4+r][*] += P·1 (matches o_acc row layout)
        o1[i] = mfma16(pfr[i][c], ones8, o1[i]);
      }
    }

    // O += P V : B-frag = Vt[d=dt*16+cl][kv=32c+quad*8 .. +8] (b128 reads)
#pragma unroll
    for (int dt = 0; dt < 4; ++dt) {
      const int vrow = dt * 16 + cl;
      const int vx = vrow & 7;
#pragma unroll
      for (int c = 0; c < 2; ++c) {
        bf16x8 bv = *(const bf16x8*)&Vc[vrow * 64 + ((4 * c + quad) ^ vx) * 8];
#pragma unroll
        for (int i = 0; i < 2; ++i)
          o_acc[i][dt] = mfma16(pfr[i][c], bv, o_acc[i][dt]);
      }
    }

    __builtin_amdgcn_s_setprio(0);
  }

  // epilogue: o1 rows (quad*4+r) align with o_acc rows
  const int b = bh / NHEADS, h = bh % NHEADS;
#pragma unroll
  for (int i = 0; i < 2; ++i)
#pragma unroll
    for (int r = 0; r < 4; ++r) {
      float inv = 1.f / o1[i][r];
      int row = b * SEQ + qb * 256 + w * 32 + i * 16 + quad * 4 + r;
#pragma unroll
      for (int dt = 0; dt < 4; ++dt)
        out[(size_t)row * DIM + h * HDIM + dt * 16 + cl] =
            f2b(o_acc[i][dt][r] * inv);
    }
}

// ---------------------------------------------------------------------------
// K3: out = attn @ w_out + b_out. fp32 output. 128x128 tile, 8 waves
// (2M x 4N, per-wave 64x32), BK=64, single-buffer 2-barrier K-loop.
// Rationale: 256x128 gave grid 320 = 1.25 blocks/CU (2-round makespan, ~62%
// utilization); 128x128 gives 640 = 2.5/CU at half the block time (~83%).
// LDS 32KB. Bijective XCD swizzle (nwg=640, %8==0).
// ---------------------------------------------------------------------------
__global__ __launch_bounds__(512) void out_gemm(
    const unsigned short* __restrict__ A, const unsigned short* __restrict__ Bt,
    const float* __restrict__ bias, float* __restrict__ C) {
  __shared__ __attribute__((aligned(16))) unsigned short As[128 * 64];
  __shared__ __attribute__((aligned(16))) unsigned short Bs[128 * 64];
  const int t = threadIdx.x;
  const int lane = t & 63, w = t >> 6;             // w 0..7
  const int quad = lane >> 4, cl = lane & 15;
  const int nxb = gridDim.x;                       // 5
  const int flatb = blockIdx.y * nxb + blockIdx.x;
  const int cpx = (nxb * gridDim.y) >> 3;          // 80
  const int swz = (flatb & 7) * cpx + (flatb >> 3);
  const int m0 = (swz / nxb) * 128, n0 = (swz % nxb) * 128;
  const int wr = (w >> 2) * 64, wc = (w & 3) * 32; // wave grid 2(M) x 4(N)

  // staging: wave w stages A rows [w*16, w*16+16) and B rows [w*16, w*16+16)
  // (2 glds each). Same per-8-row source chunk swizzle as K1.
  const int r8 = lane >> 3;
  const int sw = ((lane & 7) ^ r8) * 8;
  const unsigned short* asrc = A + (size_t)(m0 + w * 16 + r8) * DIM + sw;
  const unsigned short* bsrc = Bt + (size_t)(n0 + w * 16 + r8) * DIM + sw;

  const int x = cl & 7;
  const int aoff0 = (wr + cl) * 64 + (quad ^ x) * 8;
  const int aoff1 = (wr + cl) * 64 + ((4 + quad) ^ x) * 8;
  const int boff0 = (wc + cl) * 64 + (quad ^ x) * 8;
  const int boff1 = (wc + cl) * 64 + ((4 + quad) ^ x) * 8;

  f32x4 acc[4][2];
#pragma unroll
  for (int i = 0; i < 4; ++i)
#pragma unroll
    for (int j = 0; j < 2; ++j) acc[i][j] = (f32x4){0.f, 0.f, 0.f, 0.f};

  for (int kt = 0; kt < DIM / 64; ++kt) {
    __syncthreads();
#pragma unroll
    for (int g = 0; g < 2; ++g) {
      glds16(asrc + (size_t)g * 8 * DIM, &As[(w * 16 + g * 8) * 64]);
      glds16(bsrc + (size_t)g * 8 * DIM, &Bs[(w * 16 + g * 8) * 64]);
    }
    asrc += 64; bsrc += 64;
    __syncthreads();
#pragma unroll
    for (int ks = 0; ks < 2; ++ks) {
      const int ao = ks ? aoff1 : aoff0, bo = ks ? boff1 : boff0;
      bf16x8 af[4], bfr[2];
#pragma unroll
      for (int i = 0; i < 4; ++i) af[i] = *(const bf16x8*)&As[ao + i * 1024];
#pragma unroll
      for (int j = 0; j < 2; ++j) bfr[j] = *(const bf16x8*)&Bs[bo + j * 1024];
#pragma unroll
      for (int i = 0; i < 4; ++i)
#pragma unroll
        for (int j = 0; j < 2; ++j) acc[i][j] = mfma16(af[i], bfr[j], acc[i][j]);
    }
  }
#pragma unroll
  for (int j = 0; j < 2; ++j) {
    int cc = n0 + wc + j * 16 + cl;
    float bv = bias[cc];
#pragma unroll
    for (int i = 0; i < 4; ++i) {
#pragma unroll
      for (int r = 0; r < 4; ++r) {
        int rr = m0 + wr + i * 16 + quad * 4 + r;
        C[(size_t)rr * DIM + cc] = acc[i][j][r] + bv;
      }
    }
  }
}

// ---------------------------------------------------------------------------
extern "C" void kernel_launch(void* const* d_in, const int* in_sizes, int n_in,
                              void* d_out, int out_size, void* d_ws, size_t ws_size,
                              hipStream_t stream) {
  const float* x     = (const float*)d_in[0];
  const float* w_qkv = (const float*)d_in[1];
  const float* b_qkv = (const float*)d_in[2];
  const float* w_out = (const float*)d_in[3];
  const float* b_out = (const float*)d_in[4];
  float* out = (float*)d_out;

  unsigned short* ws = (unsigned short*)d_ws;
  unsigned short* xb      = ws;                          // 10,485,760 (aliased w/ attn_ws)
  unsigned short* wt_qkv  = ws + 10485760;               // 1,228,800
  unsigned short* wt_out  = wt_qkv + 1228800;            // 409,600
  unsigned short* qw      = wt_out + 409600;             // 10,485,760
  unsigned short* kw      = qw + 10485760;               // 10,485,760
  unsigned short* vtw     = kw + 10485760;               // 10,485,760
  unsigned short* attn_ws = xb;                          // alias: xb dead after K1

  // fused preprocessing: convert + both weight transposes in one launch
  prep<<<CONV_BLOCKS + TQKV_BLOCKS + TOUT_BX * (DIM / 32), 256, 0, stream>>>(
      x, xb, w_qkv, wt_qkv, w_out, wt_out);
  // 256x128 tile, 8 waves: grid 15 x 64 = 960 blocks (%8==0)
  qkv_gemm<<<dim3(QKVN / 128, MROWS / 256), 512, 0, stream>>>(xb, wt_qkv, b_qkv, qw, kw, vtw);
  // flat = bh + 160*qb (XCD-affine); QBLK=256, 8 waves -> 640 blocks x 512
  attn_kernel<<<dim3(NBH * (SEQ / 256)), 512, 0, stream>>>(qw, kw, vtw, attn_ws);
  // 128x128 tile, 8 waves: grid 5 x 128 = 640 blocks (%8==0)
  out_gemm<<<dim3(DIM / 128, MROWS / 128), 512, 0, stream>>>(attn_ws, wt_out, b_out, out);
}